// Round 11
// baseline (11478.442 us; speedup 1.0000x reference)
//
#include <hip/hip_runtime.h>
#include <math.h>

#define BB 32
#define TT 2048
#define HH 128

typedef float f32x2 __attribute__((ext_vector_type(2)));

// LDS-only barrier: waits LDS ops (lgkmcnt), leaves global loads/stores in
// flight across the barrier.
#define LDS_BARRIER() asm volatile("s_waitcnt lgkmcnt(0)\n\ts_barrier" ::: "memory")

// DPP helper: any DPP ctrl (quad_perm 0x00-0xFF, row_ror 0x120+n, ...).
#define QPERM_F(v, CTRL)                                                      \
  __int_as_float(__builtin_amdgcn_update_dpp(                                 \
      0, __float_as_int(v), (CTRL), 0xF, 0xF, true))

// ds_swizzle pattern must be a literal constant at the builtin call site.
template <int OFFS>
__device__ __forceinline__ float swz_xor(float v) {
  return __int_as_float(__builtin_amdgcn_ds_swizzle(__float_as_int(v), OFFS));
}

// Merging butterfly stage: lanes with bit=0 end with x summed over the lane
// pair; lanes with bit=1 end with y summed. (proven v6/R6-R10)
#define MERGE_DPP(x, y, bit, CTRL)                                            \
  ({                                                                          \
    float _k = (bit) ? (y) : (x);                                             \
    float _s = (bit) ? (x) : (y);                                             \
    _k + QPERM_F(_s, CTRL);                                                   \
  })
#define MERGE_SWZ(x, y, bit, OFFS)                                            \
  ({                                                                          \
    float _k = (bit) ? (y) : (x);                                             \
    float _s = (bit) ? (x) : (y);                                             \
    _k + swz_xor<OFFS>(_s);                                                   \
  })

__device__ __forceinline__ float tanh_fast(float s) {
  float ax = fabsf(s);
  float e = __expf(-2.0f * ax);
  float th = (1.0f - e) * __builtin_amdgcn_rcpf(1.0f + e);
  return copysignf(th, s);
}

// ---------------------------------------------------------------------------
// proj kernel: out[r, :] = emb[tokens[r]] @ Wx0 + b0   (layer-0 input proj)
// ---------------------------------------------------------------------------
template <bool GATHER>
__global__ __launch_bounds__(256) void proj_kernel(
    const float* __restrict__ src, const int* __restrict__ tokens,
    const float* __restrict__ W, const float* __restrict__ bias,
    float* __restrict__ out) {
  const int tid = threadIdx.x;
  const int jj = tid & 31;
  const int rr = tid >> 5;
  const int base = blockIdx.x * 64;

  __shared__ __align__(16) float srow[64][HH];
  __shared__ int stok[64];

  if (GATHER) {
    if (tid < 64) stok[tid] = tokens[base + tid];
    __syncthreads();
  }

#pragma unroll
  for (int i = 0; i < 8; ++i) {
    int idx = tid + i * 256;
    int row = idx >> 5;
    int c4 = idx & 31;
    const float* s = GATHER ? (src + (size_t)stok[row] * HH)
                            : (src + (size_t)(base + row) * HH);
    *(float4*)&srow[row][c4 * 4] = *(const float4*)&s[c4 * 4];
  }
  __syncthreads();

  float4 b4 = *(const float4*)&bias[jj * 4];
  float4 acc[8];
#pragma unroll
  for (int i = 0; i < 8; ++i) acc[i] = b4;

  for (int k = 0; k < HH; ++k) {
    float4 w4 = *(const float4*)&W[k * HH + jj * 4];
#pragma unroll
    for (int i = 0; i < 8; ++i) {
      float e = srow[rr * 8 + i][k];
      acc[i].x += e * w4.x;
      acc[i].y += e * w4.y;
      acc[i].z += e * w4.z;
      acc[i].w += e * w4.w;
    }
  }

#pragma unroll
  for (int i = 0; i < 8; ++i) {
    int row = base + rr * 8 + i;
    *(float4*)&out[(size_t)row * HH + jj * 4] = acc[i];
  }
}

// ---------------------------------------------------------------------------
// fused rnn kernel v11: v10 geometry + v3-style IN-LOOP weight loads.
//
// R4-R10 post-mortem: hipcc's RA never grants weight-array residency (grant
// scales DOWN with block size: 256thr->132, 512thr->88, 1024thr->52) and
// converts arrays into AGPR/scratch thrash. But v3 — the fastest structure
// measured (745 cy/step, VGPR 36) — never had resident weights either: it
// RELOADED them from L1/L2 every step via in-loop float4 loads, cleanly
// pipelined by the scheduler (~30% issue tax, no scratch). So: keep the
// fused 3-matvec superstep (2049 barriers vs 4096 — the real structural
// win), load weights inline each step, keep state tiny.
//
// Thread (jg = tid>>5 -> cols 4jg..4jg+3; p = tid&31 -> k in [4p,4p+4)):
//   per step: 12x global_load_dwordx4 (rows 4p..4p+3 of Wh0/Wx1/Wh1, +512B
//   imm per row; L2-resident 192KB/block), 24 pk_fma, 2x ds_read_b128
//   (h0,h1), merge-butterfly reduce over 32 k-lanes (bit0 col-parity dpp
//   xor1, bit1 col-pair dpp xor2, bit2 layer swz xor4, xor8 row_ror:8,
//   xor16 swz dup folds), 1 tanh/lane, 8 writer lanes per 32-half.
// woff is re-opaqued by empty asm each step so the 12 loads cannot be CSE'd
// across steps (which would re-create the spilled array).
// ---------------------------------------------------------------------------
__global__ __launch_bounds__(1024) void rnn_fused_kernel(
    const float* __restrict__ xp0, float* __restrict__ out,
    const float* __restrict__ Wh0, const float* __restrict__ Wx1,
    const float* __restrict__ Wh1, const float* __restrict__ bias1,
    const int* __restrict__ tokens) {
  const int b = blockIdx.x;
  const int tid = threadIdx.x;
  const int lane = tid & 63;
  const int p = tid & 31;   // k-split 0..31, k in [4p, 4p+4)
  const int jg = tid >> 5;  // col-group 0..31
  const int lb0 = p & 1;
  const int lb1 = (p >> 1) & 1;
  const int lb2 = (p >> 2) & 1;              // layer select after reduce
  const int mycol = 4 * jg + 2 * lb1 + lb0;  // owned col after reduce

  const float biasv = bias1[mycol];

  // mask bitmask: lane l holds bits for t in [32l, 32l+32); replicated/wave.
  const int* tok = tokens + b * TT;
  unsigned bits = 0;
#pragma unroll
  for (int i = 0; i < 8; ++i) {
    int4 tk = *(const int4*)&tok[lane * 32 + i * 4];
    bits |= (unsigned)(tk.x != 0) << (i * 4 + 0);
    bits |= (unsigned)(tk.y != 0) << (i * 4 + 1);
    bits |= (unsigned)(tk.z != 0) << (i * 4 + 2);
    bits |= (unsigned)(tk.w != 0) << (i * 4 + 3);
  }

  // double-buffered h, contiguous f32 (reads: b128 at 16p; writes: 16B
  // contiguous groups). Proven conflict-free in R10 (SQ_LDS_BANK_CONFLICT=0).
  __shared__ __align__(16) float h0s[2][HH];
  __shared__ __align__(16) float h1s[2][HH];
  if (tid < HH) {
    h0s[0][tid] = 0.0f;  // h0[-1]
    h1s[0][tid] = 0.0f;  // h1[-2]
  }

  const float* xp = xp0 + (size_t)b * TT * HH + mycol;
  float* outp = out + (size_t)b * TT * HH + mycol;

  int woff = 4 * p * HH + 4 * jg;  // my weight base (float index)

  float h = 0.0f;  // carried state for my (layer, col)
  float xc = xp[0];
  float xn = xp[HH];
  LDS_BARRIER();

#define RNN_ROW(I, QC, GC)                                                    \
  {                                                                           \
    float4 w0 = *(const float4*)&Wh0[woff + (I)*HH];                          \
    float4 wx = *(const float4*)&Wx1[woff + (I)*HH];                          \
    float4 wh = *(const float4*)&Wh1[woff + (I)*HH];                          \
    a0a += (QC) * (f32x2){w0.x, w0.y};                                        \
    a0b += (QC) * (f32x2){w0.z, w0.w};                                        \
    a1a += (QC) * (f32x2){wx.x, wx.y};                                        \
    a1b += (QC) * (f32x2){wx.z, wx.w};                                        \
    a1a += (GC) * (f32x2){wh.x, wh.y};                                        \
    a1b += (GC) * (f32x2){wh.z, wh.w};                                        \
  }

#define RNN_STEP(HRD0, HRD1, HWR0, HWR1, T, XC)                               \
  {                                                                           \
    asm volatile("" : "+v"(woff)); /* no load CSE/hoist across steps */       \
    float4 q = *(const float4*)&(HRD0)[4 * p];                                \
    float4 g = *(const float4*)&(HRD1)[4 * p];                                \
    f32x2 a0a = {0.f, 0.f}, a0b = {0.f, 0.f};                                 \
    f32x2 a1a = {0.f, 0.f}, a1b = {0.f, 0.f};                                 \
    RNN_ROW(0, q.x, g.x)                                                      \
    RNN_ROW(1, q.y, g.y)                                                      \
    RNN_ROW(2, q.z, g.z)                                                      \
    RNN_ROW(3, q.w, g.w)                                                      \
    float m0 = MERGE_DPP(a0a.x, a0a.y, lb0, 0xB1);                            \
    float m1 = MERGE_DPP(a0b.x, a0b.y, lb0, 0xB1);                            \
    float m2 = MERGE_DPP(a1a.x, a1a.y, lb0, 0xB1);                            \
    float m3 = MERGE_DPP(a1b.x, a1b.y, lb0, 0xB1);                            \
    float n0 = MERGE_DPP(m0, m1, lb1, 0x4E);                                  \
    float n1 = MERGE_DPP(m2, m3, lb1, 0x4E);                                  \
    float r = MERGE_SWZ(n0, n1, lb2, 0x101F); /* layer (xor4) */              \
    r += QPERM_F(r, 0x128);  /* xor8: row_ror:8 */                            \
    r += swz_xor<0x401F>(r); /* xor16 */                                      \
    float s = r + (lb2 ? biasv : (XC));                                       \
    unsigned wd0 = (unsigned)__builtin_amdgcn_readlane((int)bits, (T) >> 5);  \
    int mk0 = (wd0 >> ((T)&31)) & 1;                                          \
    int mk1 = 0;                                                              \
    if ((T) > 0) {                                                            \
      unsigned wd1 =                                                          \
          (unsigned)__builtin_amdgcn_readlane((int)bits, ((T)-1) >> 5);       \
      mk1 = (wd1 >> (((T)-1) & 31)) & 1;                                      \
    }                                                                         \
    int mm = lb2 ? mk1 : mk0;                                                 \
    float th = tanh_fast(s);                                                  \
    h = mm ? th : h;                                                          \
    if ((p & 24) == 0) { /* 8 writer lanes per 32-half */                     \
      if (lb2) {                                                              \
        (HWR1)[mycol] = h; /* publish h1[T-1] */                              \
        if ((T) > 0) outp[(size_t)((T)-1) * HH] = h;                          \
      } else {                                                                \
        (HWR0)[mycol] = h; /* publish h0[T] */                                \
      }                                                                       \
    }                                                                         \
    LDS_BARRIER();                                                            \
  }

  for (int t0 = 0; t0 < TT; t0 += 2) {
    float x2 = 0.0f, x3 = 0.0f;
    if (t0 + 2 < TT) x2 = xp[(size_t)(t0 + 2) * HH];
    if (t0 + 3 < TT) x3 = xp[(size_t)(t0 + 3) * HH];
    RNN_STEP(h0s[0], h1s[0], h0s[1], h1s[1], t0, xc)
    RNN_STEP(h0s[1], h1s[1], h0s[0], h1s[0], t0 + 1, xn)
    xc = x2;
    xn = x3;
  }
#undef RNN_STEP

  // tail superstep (t == TT): h1[TT-1] from h0[TT-1] and h1[TT-2]; last loop
  // step (t=2047, odd) read buf1 and wrote buf0 -> both live in buf 0.
  {
    float4 q = *(const float4*)&h0s[0][4 * p];
    float4 g = *(const float4*)&h1s[0][4 * p];
    f32x2 a1a = {0.f, 0.f}, a1b = {0.f, 0.f};
#define TAIL_ROW(I, QC, GC)                                                   \
  {                                                                           \
    float4 wx = *(const float4*)&Wx1[woff + (I)*HH];                          \
    float4 wh = *(const float4*)&Wh1[woff + (I)*HH];                          \
    a1a += (QC) * (f32x2){wx.x, wx.y};                                        \
    a1b += (QC) * (f32x2){wx.z, wx.w};                                        \
    a1a += (GC) * (f32x2){wh.x, wh.y};                                        \
    a1b += (GC) * (f32x2){wh.z, wh.w};                                        \
  }
    TAIL_ROW(0, q.x, g.x)
    TAIL_ROW(1, q.y, g.y)
    TAIL_ROW(2, q.z, g.z)
    TAIL_ROW(3, q.w, g.w)
#undef TAIL_ROW

    float m2 = MERGE_DPP(a1a.x, a1a.y, lb0, 0xB1);
    float m3 = MERGE_DPP(a1b.x, a1b.y, lb0, 0xB1);
    float n1 = MERGE_DPP(m2, m3, lb1, 0x4E);
    float r = n1 + swz_xor<0x101F>(n1);  // plain folds: only L1 values exist
    r += QPERM_F(r, 0x128);
    r += swz_xor<0x401F>(r);
    float s = r + biasv;

    const int t1 = TT - 1;
    unsigned wd1 = (unsigned)__builtin_amdgcn_readlane((int)bits, t1 >> 5);
    int mk1 = (wd1 >> (t1 & 31)) & 1;
    if (lb2) {  // lanes whose carried h is the h1 state
      float th = tanh_fast(s);
      float hv = mk1 ? th : h;
      if ((p & 24) == 0) outp[(size_t)t1 * HH] = hv;
    }
  }
#undef RNN_ROW
}

extern "C" void kernel_launch(void* const* d_in, const int* in_sizes, int n_in,
                              void* d_out, int out_size, void* d_ws,
                              size_t ws_size, hipStream_t stream) {
  const int* tokens = (const int*)d_in[0];
  const float* emb = (const float*)d_in[1];
  const float* Wx0 = (const float*)d_in[2];
  const float* Wh0 = (const float*)d_in[3];
  const float* b0 = (const float*)d_in[4];
  const float* Wx1 = (const float*)d_in[5];
  const float* Wh1 = (const float*)d_in[6];
  const float* b1 = (const float*)d_in[7];
  float* out = (float*)d_out;
  float* ws = (float*)d_ws;  // 32 MB: xp0

  const int rows = BB * TT;           // 65536
  const int proj_blocks = rows / 64;  // 1024

  proj_kernel<true><<<proj_blocks, 256, 0, stream>>>(emb, tokens, Wx0, b0, ws);
  rnn_fused_kernel<<<BB, 1024, 0, stream>>>(ws, out, Wh0, Wx1, Wh1, b1,
                                            tokens);
}

// Round 13
// 1165.373 us; speedup vs baseline: 9.8496x; 9.8496x over previous
//
#include <hip/hip_runtime.h>
#include <math.h>

#define BB 32
#define TT 2048
#define HH 128

// LDS-only barrier: waits LDS ops (lgkmcnt), leaves global loads/stores in
// flight across the barrier.
#define LDS_BARRIER() asm volatile("s_waitcnt lgkmcnt(0)\n\ts_barrier" ::: "memory")

// DPP helper: any DPP ctrl (quad_perm 0x00-0xFF, row_ror 0x120+n, ...).
#define QPERM_F(v, CTRL)                                                      \
  __int_as_float(__builtin_amdgcn_update_dpp(                                 \
      0, __float_as_int(v), (CTRL), 0xF, 0xF, true))

// ds_swizzle pattern must be a literal constant at the builtin call site.
template <int OFFS>
__device__ __forceinline__ float swz_xor(float v) {
  return __int_as_float(__builtin_amdgcn_ds_swizzle(__float_as_int(v), OFFS));
}

// Merging butterfly stage: lanes with bit=0 end with x summed over the lane
// pair; lanes with bit=1 end with y summed. (proven v6/R6-R10)
#define MERGE_DPP(x, y, bit, CTRL)                                            \
  ({                                                                          \
    float _k = (bit) ? (y) : (x);                                             \
    float _s = (bit) ? (x) : (y);                                             \
    _k + QPERM_F(_s, CTRL);                                                   \
  })
#define MERGE_SWZ(x, y, bit, OFFS)                                            \
  ({                                                                          \
    float _k = (bit) ? (y) : (x);                                             \
    float _s = (bit) ? (x) : (y);                                             \
    _k + swz_xor<OFFS>(_s);                                                   \
  })

__device__ __forceinline__ float tanh_fast(float s) {
  float ax = fabsf(s);
  float e = __expf(-2.0f * ax);
  float th = (1.0f - e) * __builtin_amdgcn_rcpf(1.0f + e);
  return copysignf(th, s);
}

// ---------------------------------------------------------------------------
// proj kernel v2: out[r, :] = emb[tokens[r]] @ Wx0 + b0.
// R12 theory: the old inner loop issued one dependent L2 float4 W-load per
// k-iter -> latency chain (~65-90us measured vs ~14us compute floor). Now:
// k-chunks of 4 with the next chunk's 4 W rows prefetched one iter ahead
// (128 FMAs/chunk ~= 256cy cover L2 latency), and float4 LDS reads for srow
// (8 ds_read_b128/chunk vs 32 scalar).
// ---------------------------------------------------------------------------
template <bool GATHER>
__global__ __launch_bounds__(256) void proj_kernel(
    const float* __restrict__ src, const int* __restrict__ tokens,
    const float* __restrict__ W, const float* __restrict__ bias,
    float* __restrict__ out) {
  const int tid = threadIdx.x;
  const int jj = tid & 31;
  const int rr = tid >> 5;
  const int base = blockIdx.x * 64;

  __shared__ __align__(16) float srow[64][HH];
  __shared__ int stok[64];

  if (GATHER) {
    if (tid < 64) stok[tid] = tokens[base + tid];
    __syncthreads();
  }

#pragma unroll
  for (int i = 0; i < 8; ++i) {
    int idx = tid + i * 256;
    int row = idx >> 5;
    int c4 = idx & 31;
    const float* s = GATHER ? (src + (size_t)stok[row] * HH)
                            : (src + (size_t)(base + row) * HH);
    *(float4*)&srow[row][c4 * 4] = *(const float4*)&s[c4 * 4];
  }
  __syncthreads();

  float4 b4 = *(const float4*)&bias[jj * 4];
  float4 acc[8];
#pragma unroll
  for (int i = 0; i < 8; ++i) acc[i] = b4;

  const float4* srow4 = (const float4*)&srow[0][0];  // [64][32]

  float4 w0 = *(const float4*)&W[0 * HH + jj * 4];
  float4 w1 = *(const float4*)&W[1 * HH + jj * 4];
  float4 w2 = *(const float4*)&W[2 * HH + jj * 4];
  float4 w3 = *(const float4*)&W[3 * HH + jj * 4];

  for (int k4 = 0; k4 < 32; ++k4) {
    // prefetch next chunk's W rows (harmless row 0 on last iter)
    int kn = (k4 + 1 < 32) ? 4 * (k4 + 1) : 0;
    float4 n0 = *(const float4*)&W[(kn + 0) * HH + jj * 4];
    float4 n1 = *(const float4*)&W[(kn + 1) * HH + jj * 4];
    float4 n2 = *(const float4*)&W[(kn + 2) * HH + jj * 4];
    float4 n3 = *(const float4*)&W[(kn + 3) * HH + jj * 4];

#pragma unroll
    for (int i = 0; i < 8; ++i) {
      float4 e = srow4[(rr * 8 + i) * 32 + k4];
      acc[i].x += e.x * w0.x + e.y * w1.x + e.z * w2.x + e.w * w3.x;
      acc[i].y += e.x * w0.y + e.y * w1.y + e.z * w2.y + e.w * w3.y;
      acc[i].z += e.x * w0.z + e.y * w1.z + e.z * w2.z + e.w * w3.z;
      acc[i].w += e.x * w0.w + e.y * w1.w + e.z * w2.w + e.w * w3.w;
    }
    w0 = n0;
    w1 = n1;
    w2 = n2;
    w3 = n3;
  }

#pragma unroll
  for (int i = 0; i < 8; ++i) {
    int row = base + rr * 8 + i;
    *(float4*)&out[(size_t)row * HH + jj * 4] = acc[i];
  }
}

// ---------------------------------------------------------------------------
// fused rnn kernel v13 = v8 (proven 1107us) + peel t=0/1 + unroll x2 with
// static buffer pointers (removes pr/pw math and the t>0 branch).
//
// R12 closed the AGPR-direct idea: gfx950 VALU cannot source AGPRs (assembler
// reject); only accvgpr_read/write + MFMA touch them. The compiler's v8 code
// (AGPR spill + per-use reads, ~206 inst/wave/step, 824cy issue/SIMD) is
// near-optimal for this structure; remaining 472cy/step is barrier + LDS
// latency + reduce/tanh serial tail. This round: pure low-risk scheduling.
// ---------------------------------------------------------------------------
__global__ __launch_bounds__(512)
__attribute__((amdgpu_waves_per_eu(2, 2))) void rnn_fused_kernel(
    const float* __restrict__ xp0, float* __restrict__ out,
    const float* __restrict__ Wh0, const float* __restrict__ Wx1,
    const float* __restrict__ Wh1, const float* __restrict__ bias1,
    const int* __restrict__ tokens) {
  const int b = blockIdx.x;
  const int tid = threadIdx.x;
  const int lane = tid & 63;
  const int lb0 = lane & 1;
  const int lb1 = (lane >> 1) & 1;
  const int lb2 = (lane >> 2) & 1;  // layer select after reduce
  const int lb3 = (lane >> 3) & 1;  // duplicate half
  const int p = lane & 15;          // k-split 0..15, k in [8p, 8p+8)
  const int jg = tid >> 4;          // col-group 0..31
  const int colbase = jg * 4;
  const int kbase = p * 8;
  const int mycol = colbase + 2 * lb1 + lb0;  // output col after reduce

  // weights: rows kbase..kbase+7, cols colbase..colbase+3 (as in v8; the
  // compiler holds some in arch VGPRs, spills the rest to AGPRs + reads).
  float w0[8][4], wx[8][4], wh[8][4];
#pragma unroll
  for (int kk = 0; kk < 8; ++kk) {
    int row = kbase + kk;
    float4 v0 = *(const float4*)&Wh0[row * HH + colbase];
    float4 v1 = *(const float4*)&Wx1[row * HH + colbase];
    float4 v2 = *(const float4*)&Wh1[row * HH + colbase];
    w0[kk][0] = v0.x; w0[kk][1] = v0.y; w0[kk][2] = v0.z; w0[kk][3] = v0.w;
    wx[kk][0] = v1.x; wx[kk][1] = v1.y; wx[kk][2] = v1.z; wx[kk][3] = v1.w;
    wh[kk][0] = v2.x; wh[kk][1] = v2.y; wh[kk][2] = v2.z; wh[kk][3] = v2.w;
  }
  const float biasv = bias1[mycol];

  // mask bitmask: lane l holds bits for t in [32l, 32l+32); replicated/wave.
  const int* tok = tokens + b * TT;
  unsigned bits = 0;
#pragma unroll
  for (int i = 0; i < 8; ++i) {
    int4 tk = *(const int4*)&tok[lane * 32 + i * 4];
    bits |= (unsigned)(tk.x != 0) << (i * 4 + 0);
    bits |= (unsigned)(tk.y != 0) << (i * 4 + 1);
    bits |= (unsigned)(tk.z != 0) << (i * 4 + 2);
    bits |= (unsigned)(tk.w != 0) << (i * 4 + 3);
  }

  // h[k] at float-offset (k>>4)*20 + (k&15)  (80 B chunk stride; proven v6)
  __shared__ __align__(16) float h0s[2][160];
  __shared__ __align__(16) float h1s[2][160];
  if (tid < 160) {
    h0s[0][tid] = 0.0f;  // h0[-1]
    h1s[0][tid] = 0.0f;  // h1[-2]
  }

  const float* xp = xp0 + (size_t)b * TT * HH + mycol;
  float* outp = out + (size_t)b * TT * HH + mycol;

  const int roff = (p >> 1) * 20 + (p & 1) * 8;        // my k-slice read offset
  const int wslot = (mycol >> 4) * 20 + (mycol & 15);  // my publish slot

  float h = 0.0f;  // carried state for my (layer, col)
  float xc = xp[0];
  float xn = xp[HH];
  LDS_BARRIER();

#define RNN_STEP(RD0, RD1, WR0, WR1, T, XCV)                                  \
  {                                                                           \
    const float* hb0 = &(RD0)[roff];                                          \
    const float* hb1 = &(RD1)[roff];                                          \
    float4 hA0 = *(const float4*)&hb0[0];                                     \
    float4 hB0 = *(const float4*)&hb0[4];                                     \
    float4 hA1 = *(const float4*)&hb1[0];                                     \
    float4 hB1 = *(const float4*)&hb1[4];                                     \
    float hq[8] = {hA0.x, hA0.y, hA0.z, hA0.w, hB0.x, hB0.y, hB0.z, hB0.w};   \
    float hg[8] = {hA1.x, hA1.y, hA1.z, hA1.w, hB1.x, hB1.y, hB1.z, hB1.w};   \
    float x2 = 0.0f;                                                          \
    if ((T) + 2 < TT) x2 = xp[(size_t)((T) + 2) * HH];                        \
    float a0[4] = {0.f, 0.f, 0.f, 0.f};                                       \
    float a1[4] = {0.f, 0.f, 0.f, 0.f};                                       \
    _Pragma("unroll") for (int kk = 0; kk < 8; ++kk) {                        \
      _Pragma("unroll") for (int c = 0; c < 4; ++c) {                         \
        a0[c] += w0[kk][c] * hq[kk];                                          \
        a1[c] += wx[kk][c] * hq[kk];                                          \
        a1[c] += wh[kk][c] * hg[kk];                                          \
      }                                                                       \
    }                                                                         \
    float m0 = MERGE_DPP(a0[0], a0[1], lb0, 0xB1);                            \
    float m1 = MERGE_DPP(a0[2], a0[3], lb0, 0xB1);                            \
    float m2 = MERGE_DPP(a1[0], a1[1], lb0, 0xB1);                            \
    float m3 = MERGE_DPP(a1[2], a1[3], lb0, 0xB1);                            \
    float n0 = MERGE_DPP(m0, m1, lb1, 0x4E);                                  \
    float n1 = MERGE_DPP(m2, m3, lb1, 0x4E);                                  \
    float r = MERGE_SWZ(n0, n1, lb2, 0x101F); /* layer (xor4) */              \
    r += QPERM_F(r, 0x128); /* xor8 == row_ror:8 within 16-group */           \
    float s = r + (lb2 ? biasv : (XCV));                                      \
    unsigned wd0 = (unsigned)__builtin_amdgcn_readlane((int)bits, (T) >> 5);  \
    int mk0 = (wd0 >> ((T)&31)) & 1;                                          \
    int mk1 = 0;                                                              \
    if ((T) > 0) {                                                            \
      unsigned wd1 =                                                          \
          (unsigned)__builtin_amdgcn_readlane((int)bits, ((T)-1) >> 5);       \
      mk1 = (wd1 >> (((T)-1) & 31)) & 1;                                      \
    }                                                                         \
    int mm = lb2 ? mk1 : mk0;                                                 \
    float th = tanh_fast(s);                                                  \
    h = mm ? th : h;                                                          \
    if (!lb3) {                                                               \
      if (lb2) {                                                              \
        (WR1)[wslot] = h; /* publish h1[T-1] */                               \
        if ((T) > 0) outp[(size_t)((T)-1) * HH] = h;                          \
      } else {                                                                \
        (WR0)[wslot] = h; /* publish h0[T] */                                 \
      }                                                                       \
    }                                                                         \
    LDS_BARRIER();                                                            \
    xc = xn;                                                                  \
    xn = x2;                                                                  \
  }

  // peel t=0 (mk1 folds to 0, no out write) and t=1
  RNN_STEP(h0s[0], h1s[0], h0s[1], h1s[1], 0, xc)
  RNN_STEP(h0s[1], h1s[1], h0s[0], h1s[0], 1, xc)

  // main loop, unrolled x2 with static buffer pointers (t=2..2047, 1023 pairs)
  for (int t = 2; t < TT; t += 2) {
    RNN_STEP(h0s[0], h1s[0], h0s[1], h1s[1], t, xc)
    RNN_STEP(h0s[1], h1s[1], h0s[0], h1s[0], t + 1, xc)
  }
#undef RNN_STEP

  // tail superstep (t == TT): h1[TT-1] from h0[TT-1] and h1[TT-2]; last loop
  // step (t=2047, odd) read buf1 and wrote buf0 -> both live in buf 0.
  {
    const float* hb0 = &h0s[0][roff];
    const float* hb1 = &h1s[0][roff];
    float4 hA0 = *(const float4*)&hb0[0];
    float4 hB0 = *(const float4*)&hb0[4];
    float4 hA1 = *(const float4*)&hb1[0];
    float4 hB1 = *(const float4*)&hb1[4];
    float hq[8] = {hA0.x, hA0.y, hA0.z, hA0.w, hB0.x, hB0.y, hB0.z, hB0.w};
    float hg[8] = {hA1.x, hA1.y, hA1.z, hA1.w, hB1.x, hB1.y, hB1.z, hB1.w};

    float a1[4] = {0.f, 0.f, 0.f, 0.f};
#pragma unroll
    for (int kk = 0; kk < 8; ++kk) {
#pragma unroll
      for (int c = 0; c < 4; ++c) {
        a1[c] += wx[kk][c] * hq[kk];
        a1[c] += wh[kk][c] * hg[kk];
      }
    }

    float m2 = MERGE_DPP(a1[0], a1[1], lb0, 0xB1);
    float m3 = MERGE_DPP(a1[2], a1[3], lb0, 0xB1);
    float n1 = MERGE_DPP(m2, m3, lb1, 0x4E);
    float r = n1 + swz_xor<0x101F>(n1);  // plain folds: only L1 values exist
    r += QPERM_F(r, 0x128);
    float s = r + biasv;

    const int t1 = TT - 1;
    unsigned wd1 = (unsigned)__builtin_amdgcn_readlane((int)bits, t1 >> 5);
    int mk1 = (wd1 >> (t1 & 31)) & 1;
    if (lb2) {  // lanes whose carried h is the h1 state
      float th = tanh_fast(s);
      float hv = mk1 ? th : h;
      if (!lb3) outp[(size_t)t1 * HH] = hv;
    }
  }
}

extern "C" void kernel_launch(void* const* d_in, const int* in_sizes, int n_in,
                              void* d_out, int out_size, void* d_ws,
                              size_t ws_size, hipStream_t stream) {
  const int* tokens = (const int*)d_in[0];
  const float* emb = (const float*)d_in[1];
  const float* Wx0 = (const float*)d_in[2];
  const float* Wh0 = (const float*)d_in[3];
  const float* b0 = (const float*)d_in[4];
  const float* Wx1 = (const float*)d_in[5];
  const float* Wh1 = (const float*)d_in[6];
  const float* b1 = (const float*)d_in[7];
  float* out = (float*)d_out;
  float* ws = (float*)d_ws;  // 32 MB: xp0

  const int rows = BB * TT;           // 65536
  const int proj_blocks = rows / 64;  // 1024

  proj_kernel<true><<<proj_blocks, 256, 0, stream>>>(emb, tokens, Wx0, b0, ws);
  rnn_fused_kernel<<<BB, 512, 0, stream>>>(ws, out, Wh0, Wx1, Wh1, b1, tokens);
}